// Round 10
// baseline (14946.371 us; speedup 1.0000x reference)
//
#include <hip/hip_runtime.h>

// ---------------------------------------------------------------------------
// 2-layer tanh RNN, B=64, T=512, I=256, H=512.  Round 15: layer-per-block --
// the recurrence never crosses a block boundary.
//   Evidence R4-R14: every per-step cross-block exchange costs ~2 serial LLC
//   round-trips (~3.5us/step) regardless of protocol (flags == sentinel).
//   Fix: one 1024-thr block computes a FULL [16 batch x 512 H] layer step;
//   h-state lives in an LDS double buffer (never leaves the CU).
//   - L0 (blocks 0-3): ZERO waits.  LDS read -> 32 MFMA/wave (4 split acc
//     chains) -> tanh -> LDS writeback + coalesced sc1 publish of out0 ->
//     vmcnt(0) -> 1 barrier -> flag.  Runs at pure compute speed.
//   - L1 (blocks 4-7): own h1 recurrence intra-block; out0(t+1) is a
//     feed-forward gate (L0 runs ahead -> flag pre-satisfied); 64 MFMA/wave
//     (hh+ih fused into same accumulators, no pair reduce); no per-step h1
//     publish (only final h1(T) for finalize).  2 barriers/step.
//   - Weights stream from L2 in-loop (R13-proven regime); per-iteration
//     pointer laundering blocks hoist/spill; constant indexing only.
//   - xw = x@Wih0+biases precomputed into d_out (proven aliasing).
// ---------------------------------------------------------------------------

#define kB 64
#define kT 512
#define kI 256
#define kH 512
#define kBH (kB * kH)   // 32768

typedef _Float16 half8 __attribute__((ext_vector_type(8)));
typedef float floatx4 __attribute__((ext_vector_type(4)));
typedef unsigned u32x4 __attribute__((ext_vector_type(4)));

#define MFMA(a, b, c) __builtin_amdgcn_mfma_f32_16x16x32_f16(a, b, c, 0, 0, 0)

// ws layout (bytes)
constexpr size_t W16_B   = 0;                      // wih0 fp16, 256 KB
constexpr size_t WH0_B   = 1u * 1024 * 1024;       // whh0 fp16, 512 KB
constexpr size_t WI1_B   = WH0_B + 512u * 1024;    // wih1 fp16, 512 KB
constexpr size_t WH1_B   = WI1_B + 512u * 1024;    // whh1 fp16, 512 KB
constexpr size_t OUT0M_B = 16u * 1024 * 1024;                     // [T+1][B][H] fp16
constexpr size_t H1M_B   = OUT0M_B + (size_t)(kT + 1) * kBH * 2;  // [T+1][B][H] fp16
constexpr size_t CNT_B   = H1M_B + (size_t)(kT + 1) * kBH * 2;    // flags (1024 ints)

__device__ inline void agent_store16(void* p, u32x4 v) {
    asm volatile("global_store_dwordx4 %0, %1, off sc1" :: "v"(p), "v"(v) : "memory");
}
__device__ inline int aload(const int* p) {
    return __hip_atomic_load(p, __ATOMIC_RELAXED, __HIP_MEMORY_SCOPE_AGENT);
}
__device__ inline void wait_slot(const int* p, int target) {
    int g = 0;
    while (aload(p) < target) if (++g > 100000000) break;   // fail-wrong, not hang
    asm volatile("" ::: "memory");   // keep gated loads below the gate
}

__device__ inline float fast_tanh(float x) {
    float e = __expf(2.f * x);
    return 1.f - 2.f / (e + 1.f);   // exact +-1 saturation, no NaN
}

__device__ inline half8 cvt8(const float* p) {
    const float4* p4 = (const float4*)p;
    float4 a = p4[0], b = p4[1];
    half8 h;
    h[0] = (_Float16)a.x; h[1] = (_Float16)a.y; h[2] = (_Float16)a.z; h[3] = (_Float16)a.w;
    h[4] = (_Float16)b.x; h[5] = (_Float16)b.y; h[6] = (_Float16)b.z; h[7] = (_Float16)b.w;
    return h;
}

// ---------------------------------------------------------------------------
__global__ void setup_kernel(const float* __restrict__ h0,
                             const float* __restrict__ wih0, const float* __restrict__ whh0,
                             const float* __restrict__ wih1, const float* __restrict__ whh1,
                             _Float16* __restrict__ w16, _Float16* __restrict__ wh0_16,
                             _Float16* __restrict__ wi1_16, _Float16* __restrict__ wh1_16,
                             _Float16* __restrict__ out0m, _Float16* __restrict__ h1m,
                             int* __restrict__ cnt) {
    size_t tid = (size_t)blockIdx.x * blockDim.x + threadIdx.x;
    size_t stride = (size_t)gridDim.x * blockDim.x;
    for (size_t i = tid; i < (size_t)kH * kI; i += stride) w16[i] = (_Float16)wih0[i];
    for (size_t i = tid; i < (size_t)kH * kH; i += stride) {
        wh0_16[i] = (_Float16)whh0[i];
        wi1_16[i] = (_Float16)wih1[i];
        wh1_16[i] = (_Float16)whh1[i];
    }
    for (size_t i = tid; i < kBH; i += stride) {
        out0m[i] = (_Float16)h0[i];          // h(0) layer0 -> slab 0
        h1m[i]   = (_Float16)h0[kBH + i];    // h(0) layer1 -> slab 0
    }
    if (tid < 1024) cnt[tid] = 0;
}

// xw[b][t][c] = sum_i x[b,t,i]*Wih0[c,i] + bih0[c] + bhh0[c]   (fp32, into d_out)
__global__ __launch_bounds__(256) void xw_kernel(
    const float* __restrict__ x, const _Float16* __restrict__ w16,
    const float* __restrict__ bih, const float* __restrict__ bhh, float* xw) {
    const int mb = blockIdx.x >> 3, nb = blockIdx.x & 7;
    const int wave = threadIdx.x >> 6, lane = threadIdx.x & 63;
    const int r = lane & 15, q = lane >> 4;
    const int m0 = mb * 64 + wave * 16;
    half8 a[8];
#pragma unroll
    for (int ko = 0; ko < 8; ++ko)
        a[ko] = cvt8(x + (size_t)(m0 + r) * kI + ko * 32 + q * 8);
#pragma unroll
    for (int ct = 0; ct < 4; ++ct) {
        const int cc = nb * 64 + ct * 16 + r;
        const float bias = bih[cc] + bhh[cc];
        floatx4 acc = {bias, bias, bias, bias};
#pragma unroll
        for (int ko = 0; ko < 8; ++ko) {
            half8 b = *(const half8*)(w16 + (size_t)cc * kI + ko * 32 + q * 8);
            acc = MFMA(a[ko], b, acc);
        }
#pragma unroll
        for (int j = 0; j < 4; ++j)
            xw[(size_t)(m0 + q * 4 + j) * kH + cc] = acc[j];
    }
}

// ---------------------------------------------------------------------------
__global__ __launch_bounds__(1024) void scan_kernel(
    const float* xw,                       // = d_out (fp32 [B][T][H]), layer0 reads
    _Float16* out0m, _Float16* h1m,
    float* out1,                           // = d_out, layer1 writes
    const _Float16* __restrict__ wh0_16,
    const _Float16* __restrict__ wi1_16, const _Float16* __restrict__ wh1_16,
    const float* __restrict__ bih1, const float* __restrict__ bhh1,
    int* cnt) {
    __shared__ __align__(16) char smem[65536];

    const int blk = blockIdx.x;
    const int tid = threadIdx.x;
    const int wave = tid >> 6, lane = tid & 63;
    const int r = lane & 15, q = lane >> 4;
    const int rb = r << 10, swz = (r & 7) << 4;      // MFMA A-read addressing
    const int rr = lane >> 2, cg = lane & 3;         // epilogue transpose roles
    const int srow = tid >> 6, sunit = tid & 63;     // stage roles (16B/thread)
    const int sdoff = ((srow << 10) | (sunit << 4)) ^ ((srow & 7) << 4);
    const int tdoff = (((rr << 10) | (wave * 64 + cg * 16)) ^ ((rr & 7) << 4));

    if (blk < 4) {
        // ===== layer 0: one block per group; 16 waves x 32 cols, full-K =====
        const int g = blk, b0 = g * 16, cb = wave * 32;
        const _Float16* wA = wh0_16 + (size_t)(cb + r) * kH;
        const _Float16* wB = wh0_16 + (size_t)(cb + 16 + r) * kH;
        char* Hb = smem;                             // [2][16KB] h0 state dbuf
        char* ts = smem + 32768 + wave * 1024;       // per-wave [16][32] fp16
        int* myf = cnt + g * 32;

        // prestage h0(0)
        {
            u32x4 v = *(const u32x4*)(out0m + (size_t)(b0 + srow) * kH + sunit * 8);
            *(u32x4*)(Hb + sdoff) = v;
        }
        __syncthreads();

        for (int t = 0; t < kT; ++t) {
            char* bufR = Hb + (t & 1) * 16384;
            char* bufW = Hb + ((t + 1) & 1) * 16384;
            asm volatile("" : "+v"(wA), "+v"(wB));   // block load hoisting across t
            float xa[4], xb[4];
#pragma unroll
            for (int j = 0; j < 4; ++j) {
                const float* xp = xw + ((size_t)(b0 + q * 4 + j) * kT + t) * kH + cb + r;
                xa[j] = xp[0]; xb[j] = xp[16];
            }
            floatx4 a0 = {0.f,0.f,0.f,0.f}, a1 = {0.f,0.f,0.f,0.f};
            floatx4 c0 = {0.f,0.f,0.f,0.f}, c1 = {0.f,0.f,0.f,0.f};
#pragma unroll
            for (int ks = 0; ks < 8; ++ks) {
                half8 la = *(const half8*)(bufR + ((rb | (ks << 6) | (q << 4)) ^ swz));
                a0 = MFMA(la, *(const half8*)(wA + ks * 32 + q * 8), a0);
                c0 = MFMA(la, *(const half8*)(wB + ks * 32 + q * 8), c0);
            }
#pragma unroll
            for (int ks = 8; ks < 16; ++ks) {
                half8 la = *(const half8*)(bufR + ((rb | (ks << 6) | (q << 4)) ^ swz));
                a1 = MFMA(la, *(const half8*)(wA + ks * 32 + q * 8), a1);
                c1 = MFMA(la, *(const half8*)(wB + ks * 32 + q * 8), c1);
            }
            floatx4 accA = a0 + a1, accB = c0 + c1;
            // epilogue: tanh -> per-wave transpose
#pragma unroll
            for (int j = 0; j < 4; ++j) {
                float vA = fast_tanh(accA[j] + xa[j]);
                float vB = fast_tanh(accB[j] + xb[j]);
                *(_Float16*)(ts + (q * 4 + j) * 64 + r * 2) = (_Float16)vA;
                *(_Float16*)(ts + (q * 4 + j) * 64 + 32 + r * 2) = (_Float16)vB;
            }
            asm volatile("s_waitcnt lgkmcnt(0)" ::: "memory");
            u32x4 tv = *(const u32x4*)(ts + rr * 64 + cg * 16);
            agent_store16(out0m + (size_t)(t + 1) * kBH + (size_t)(b0 + rr) * kH
                          + wave * 32 + cg * 8, tv);          // publish for L1
            *(u32x4*)(bufW + tdoff) = tv;                     // next h0 state (LDS)
            // drain -> ONE barrier -> flag
            asm volatile("" ::: "memory");
            __builtin_amdgcn_s_waitcnt(0x0F70);      // vmcnt(0)
            __syncthreads();
            if (tid == 0)
                __hip_atomic_store(myf, t + 1, __ATOMIC_RELAXED, __HIP_MEMORY_SCOPE_AGENT);
        }
    } else {
        // ===== layer 1: one block per group; 16 waves x 32 cols, hh+ih fused =====
        const int g = blk - 4, b0 = g * 16, cb = wave * 32;
        const _Float16* hA = wh1_16 + (size_t)(cb + r) * kH;
        const _Float16* hB = wh1_16 + (size_t)(cb + 16 + r) * kH;
        const _Float16* iA = wi1_16 + (size_t)(cb + r) * kH;
        const _Float16* iB = wi1_16 + (size_t)(cb + 16 + r) * kH;
        const float biasA = bih1[cb + r] + bhh1[cb + r];
        const float biasB = bih1[cb + 16 + r] + bhh1[cb + 16 + r];
        char* Hb = smem;                             // [2][16KB] h1 state dbuf
        char* Ob = smem + 32768;                     // [16KB] out0(t+1) stage
        char* ts = smem + 49152 + wave * 1024;       // per-wave [16][32] fp16
        const int* lf = cnt + g * 32;

        // prestage h1(0)
        {
            u32x4 v = *(const u32x4*)(h1m + (size_t)(b0 + srow) * kH + sunit * 8);
            *(u32x4*)(Hb + sdoff) = v;
        }
        __syncthreads();

        for (int t = 0; t < kT; ++t) {
            char* bufR = Hb + (t & 1) * 16384;
            char* bufW = Hb + ((t + 1) & 1) * 16384;
            // gate on L0 (normally pre-satisfied), stage out0(t+1)
            wait_slot(lf, t + 1);
            {
                u32x4 ov = *(const u32x4*)(out0m + (size_t)(t + 1) * kBH
                                           + (size_t)(b0 + srow) * kH + sunit * 8);
                *(u32x4*)(Ob + sdoff) = ov;
            }
            __syncthreads();                         // S: stage + prev-h visible
            asm volatile("" : "+v"(hA), "+v"(hB), "+v"(iA), "+v"(iB));
            floatx4 a0 = {0.f,0.f,0.f,0.f}, a1 = {0.f,0.f,0.f,0.f};
            floatx4 c0 = {0.f,0.f,0.f,0.f}, c1 = {0.f,0.f,0.f,0.f};
#pragma unroll
            for (int ks = 0; ks < 8; ++ks) {
                const int off = (rb | (ks << 6) | (q << 4)) ^ swz;
                half8 lh = *(const half8*)(bufR + off);
                a0 = MFMA(lh, *(const half8*)(hA + ks * 32 + q * 8), a0);
                c0 = MFMA(lh, *(const half8*)(hB + ks * 32 + q * 8), c0);
                half8 lo = *(const half8*)(Ob + off);
                a0 = MFMA(lo, *(const half8*)(iA + ks * 32 + q * 8), a0);
                c0 = MFMA(lo, *(const half8*)(iB + ks * 32 + q * 8), c0);
            }
#pragma unroll
            for (int ks = 8; ks < 16; ++ks) {
                const int off = (rb | (ks << 6) | (q << 4)) ^ swz;
                half8 lh = *(const half8*)(bufR + off);
                a1 = MFMA(lh, *(const half8*)(hA + ks * 32 + q * 8), a1);
                c1 = MFMA(lh, *(const half8*)(hB + ks * 32 + q * 8), c1);
                half8 lo = *(const half8*)(Ob + off);
                a1 = MFMA(lo, *(const half8*)(iA + ks * 32 + q * 8), a1);
                c1 = MFMA(lo, *(const half8*)(iB + ks * 32 + q * 8), c1);
            }
            floatx4 accA = a0 + a1, accB = c0 + c1;
            float* o1p = out1 + ((size_t)(b0 + q * 4) * kT + t) * kH + cb + r;
#pragma unroll
            for (int j = 0; j < 4; ++j) {
                float vA = fast_tanh(accA[j] + biasA);
                float vB = fast_tanh(accB[j] + biasB);
                o1p[(size_t)j * kT * kH] = vA;       // out1 fp32 (fire-and-forget)
                o1p[(size_t)j * kT * kH + 16] = vB;
                *(_Float16*)(ts + (q * 4 + j) * 64 + r * 2) = (_Float16)vA;
                *(_Float16*)(ts + (q * 4 + j) * 64 + 32 + r * 2) = (_Float16)vB;
            }
            asm volatile("s_waitcnt lgkmcnt(0)" ::: "memory");
            u32x4 tv = *(const u32x4*)(ts + rr * 64 + cg * 16);
            *(u32x4*)(bufW + tdoff) = tv;            // next h1 state (LDS only)
            if (t == kT - 1)                          // final h1(T) for finalize
                *(u32x4*)(h1m + (size_t)kT * kBH + (size_t)(b0 + rr) * kH
                          + wave * 32 + cg * 8) = tv;
            __syncthreads();                         // E: h-writes + Ob reuse fence
        }
    }
}

__global__ void finalize_kernel(const _Float16* __restrict__ out0m,
                                const _Float16* __restrict__ h1m,
                                float* __restrict__ out) {
    int idx = blockIdx.x * blockDim.x + threadIdx.x;  // 0 .. 65535
    float* hn = out + (size_t)kB * kT * kH;
    if (idx < kBH) hn[idx] = (float)out0m[(size_t)kT * kBH + idx];
    else hn[idx] = (float)h1m[(size_t)kT * kBH + (idx - kBH)];
}

extern "C" void kernel_launch(void* const* d_in, const int* in_sizes, int n_in,
                              void* d_out, int out_size, void* d_ws, size_t ws_size,
                              hipStream_t stream) {
    const float* x    = (const float*)d_in[0];
    const float* h0in = (const float*)d_in[1];
    const float* wih0 = (const float*)d_in[2];
    const float* whh0 = (const float*)d_in[3];
    const float* bih0 = (const float*)d_in[4];
    const float* bhh0 = (const float*)d_in[5];
    const float* wih1 = (const float*)d_in[6];
    const float* whh1 = (const float*)d_in[7];
    const float* bih1 = (const float*)d_in[8];
    const float* bhh1 = (const float*)d_in[9];
    float* out = (float*)d_out;
    char* ws = (char*)d_ws;

    _Float16* w16    = (_Float16*)(ws + W16_B);
    _Float16* wh0_16 = (_Float16*)(ws + WH0_B);
    _Float16* wi1_16 = (_Float16*)(ws + WI1_B);
    _Float16* wh1_16 = (_Float16*)(ws + WH1_B);
    _Float16* out0m  = (_Float16*)(ws + OUT0M_B);
    _Float16* h1m    = (_Float16*)(ws + H1M_B);
    int* cnt         = (int*)(ws + CNT_B);

    setup_kernel<<<2048, 256, 0, stream>>>(h0in, wih0, whh0, wih1, whh1,
                                           w16, wh0_16, wi1_16, wh1_16, out0m, h1m, cnt);
    xw_kernel<<<4096, 256, 0, stream>>>(x, w16, bih0, bhh0, out);
    scan_kernel<<<8, 1024, 0, stream>>>(out, out0m, h1m, out,
                                        wh0_16, wi1_16, wh1_16, bih1, bhh1, cnt);
    finalize_kernel<<<256, 256, 0, stream>>>(out0m, h1m, out);
}

// Round 11
// 4394.991 us; speedup vs baseline: 3.4008x; 3.4008x over previous
//
#include <hip/hip_runtime.h>

// ---------------------------------------------------------------------------
// 2-layer tanh RNN, B=64, T=512, I=256, H=512.  Round 16: R13 champion +
// retained-own-state.  Blocks stop re-staging from global the columns they
// computed themselves last step:
//   - epilogue writes its output slice into the NEXT LDS stage tile (2B
//     scatter, swizzle-consistent) in addition to the global publish.
//   - in-loop staging fetches ONLY peer columns (L0: 8KB not 16KB; L1-hh:
//     12KB not 16KB); own-K MFMAs (L0: 8/16, L1-hh: 4/16) hoisted BEFORE
//     the flag wait -- off the serial chain.
//   - stage tiles double-buffered (epilogue writes parity t+1 while other
//     waves still read parity t; P-barrier separates reuse).
//   - all weight arrays constant-indexed (own/peer split at load; rule-#20
//     safe).  Everything else R13 verbatim: cooperative coalesced staging,
//     R5 flag protocol (drain -> barrier -> flag, 128B-spaced flags), MFMA
//     mapping, LDS swizzle, fp16 weights, fast_tanh, xw into d_out.
//   R15 lesson honored: keep 24 blocks (weight stream spread), no pointer
//   laundering, no per-lane direct peer loads.
// ---------------------------------------------------------------------------

#define kB 64
#define kT 512
#define kI 256
#define kH 512
#define kBH (kB * kH)   // 32768

typedef _Float16 half8 __attribute__((ext_vector_type(8)));
typedef float floatx4 __attribute__((ext_vector_type(4)));
typedef unsigned u32x4 __attribute__((ext_vector_type(4)));
typedef unsigned u32x2 __attribute__((ext_vector_type(2)));

#define MFMA(a, b, c) __builtin_amdgcn_mfma_f32_16x16x32_f16(a, b, c, 0, 0, 0)

// ws layout (bytes)
constexpr size_t W16_B   = 0;                      // wih0 fp16, 256 KB
constexpr size_t WH0_B   = 1u * 1024 * 1024;       // whh0 fp16, 512 KB
constexpr size_t WI1_B   = WH0_B + 512u * 1024;    // wih1 fp16, 512 KB
constexpr size_t WH1_B   = WI1_B + 512u * 1024;    // whh1 fp16, 512 KB
constexpr size_t OUT0M_B = 16u * 1024 * 1024;                     // [T+1][B][H] fp16
constexpr size_t H1M_B   = OUT0M_B + (size_t)(kT + 1) * kBH * 2;  // [T+1][B][H] fp16
constexpr size_t CNT_B   = H1M_B + (size_t)(kT + 1) * kBH * 2;    // flags (1024 ints)

__device__ inline void agent_store8(void* p, u32x2 v) {
    asm volatile("global_store_dwordx2 %0, %1, off sc1" :: "v"(p), "v"(v) : "memory");
}
__device__ inline int aload(const int* p) {
    return __hip_atomic_load(p, __ATOMIC_RELAXED, __HIP_MEMORY_SCOPE_AGENT);
}
// flags live 128B apart (index * 32 ints)
__device__ inline void wait_slot(const int* p, int target) {
    int g = 0;
    while (aload(p) < target) if (++g > 100000000) break;   // fail-wrong, not hang
    asm volatile("" ::: "memory");   // keep gated loads below the gate
}
__device__ inline void wait_pair(const int* f, int target) {
    const int* p = f + (threadIdx.x & 1) * 32;
    int g = 0;
    for (;;) { int v = aload(p); if (__all(v >= target)) break; if (++g > 100000000) break; }
    asm volatile("" ::: "memory");
}
__device__ inline void wait_quad(const int* f, int own, int target) {
    const int idx = threadIdx.x & 3;
    const int* p = f + idx * 32;
    int g = 0;
    for (;;) {
        int v = (idx == own) ? target : aload(p);
        if (__all(v >= target)) break;
        if (++g > 100000000) break;
    }
    asm volatile("" ::: "memory");
}

__device__ inline float fast_tanh(float x) {
    float e = __expf(2.f * x);
    return 1.f - 2.f / (e + 1.f);   // exact +-1 saturation, no NaN
}

__device__ inline half8 cvt8(const float* p) {
    const float4* p4 = (const float4*)p;
    float4 a = p4[0], b = p4[1];
    half8 h;
    h[0] = (_Float16)a.x; h[1] = (_Float16)a.y; h[2] = (_Float16)a.z; h[3] = (_Float16)a.w;
    h[4] = (_Float16)b.x; h[5] = (_Float16)b.y; h[6] = (_Float16)b.z; h[7] = (_Float16)b.w;
    return h;
}

// ---------------------------------------------------------------------------
__global__ void setup_kernel(const float* __restrict__ h0,
                             const float* __restrict__ wih0, const float* __restrict__ whh0,
                             const float* __restrict__ wih1, const float* __restrict__ whh1,
                             _Float16* __restrict__ w16, _Float16* __restrict__ wh0_16,
                             _Float16* __restrict__ wi1_16, _Float16* __restrict__ wh1_16,
                             _Float16* __restrict__ out0m, _Float16* __restrict__ h1m,
                             int* __restrict__ cnt) {
    size_t tid = (size_t)blockIdx.x * blockDim.x + threadIdx.x;
    size_t stride = (size_t)gridDim.x * blockDim.x;
    for (size_t i = tid; i < (size_t)kH * kI; i += stride) w16[i] = (_Float16)wih0[i];
    for (size_t i = tid; i < (size_t)kH * kH; i += stride) {
        wh0_16[i] = (_Float16)whh0[i];
        wi1_16[i] = (_Float16)wih1[i];
        wh1_16[i] = (_Float16)whh1[i];
    }
    for (size_t i = tid; i < kBH; i += stride) {
        out0m[i] = (_Float16)h0[i];          // h(0) layer0 -> slab 0
        h1m[i]   = (_Float16)h0[kBH + i];    // h(0) layer1 -> slab 0
    }
    if (tid < 1024) cnt[tid] = 0;
}

// xw[b][t][c] = sum_i x[b,t,i]*Wih0[c,i] + bih0[c] + bhh0[c]   (fp32, into d_out)
__global__ __launch_bounds__(256) void xw_kernel(
    const float* __restrict__ x, const _Float16* __restrict__ w16,
    const float* __restrict__ bih, const float* __restrict__ bhh, float* xw) {
    const int mb = blockIdx.x >> 3, nb = blockIdx.x & 7;
    const int wave = threadIdx.x >> 6, lane = threadIdx.x & 63;
    const int r = lane & 15, q = lane >> 4;
    const int m0 = mb * 64 + wave * 16;
    half8 a[8];
#pragma unroll
    for (int ko = 0; ko < 8; ++ko)
        a[ko] = cvt8(x + (size_t)(m0 + r) * kI + ko * 32 + q * 8);
#pragma unroll
    for (int ct = 0; ct < 4; ++ct) {
        const int cc = nb * 64 + ct * 16 + r;
        const float bias = bih[cc] + bhh[cc];
        floatx4 acc = {bias, bias, bias, bias};
#pragma unroll
        for (int ko = 0; ko < 8; ++ko) {
            half8 b = *(const half8*)(w16 + (size_t)cc * kI + ko * 32 + q * 8);
            acc = MFMA(a[ko], b, acc);
        }
#pragma unroll
        for (int j = 0; j < 4; ++j)
            xw[(size_t)(m0 + q * 4 + j) * kH + cc] = acc[j];
    }
}

// ---------------------------------------------------------------------------
__global__ __launch_bounds__(1024) void scan_kernel(
    const float* xw,                       // = d_out (fp32 [B][T][H]), layer0 reads
    _Float16* out0m, _Float16* h1m,
    float* out1,                           // = d_out, layer1 writes
    const _Float16* __restrict__ wh0_16,
    const _Float16* __restrict__ wi1_16, const _Float16* __restrict__ wh1_16,
    const float* __restrict__ bih1, const float* __restrict__ bhh1,
    int* cnt) {
    __shared__ __align__(16) char smem[61440];
    // L0: Hst[2][16KB] @0 ; ts @32768 (8KB)
    // L1: Hst[2][16KB] @0 ; Ob @32768 (16KB) ; red @49152 (8KB) ; ts @57344 (4KB)

    const int blk = blockIdx.x;
    const int tid = threadIdx.x;
    const int wave = tid >> 6, lane = tid & 63;
    const int r = lane & 15, q = lane >> 4;
    const int rb = r << 10, swz = (r & 7) << 4;      // MFMA A-read addressing
    const int rr = lane >> 2, cg = lane & 3;         // publish-transpose roles
    // full-tile prestage roles (16B/thread over [16][512] fp16)
    const int srow = tid >> 6, sunit = tid & 63;
    const int sdoff = ((srow << 10) | (sunit << 4)) ^ ((srow & 7) << 4);

    if (blk < 8) {
        // ===== layer 0: 4 groups x 2 halves, 16 waves x 16 cols, full-K =====
        const int g = blk >> 1, hf = blk & 1;
        const int b0 = g * 16;
        const int cc = hf * 256 + wave * 16 + r;     // weight row / output col
        const _Float16* wrow = wh0_16 + (size_t)cc * kH;
        half8 wfOwn[8], wfPeer[8];                   // constant-indexed split
#pragma unroll
        for (int i = 0; i < 8; ++i) {
            wfOwn[i]  = *(const half8*)(wrow + hf * 256 + i * 32 + q * 8);
            wfPeer[i] = *(const half8*)(wrow + (hf ^ 1) * 256 + i * 32 + q * 8);
        }
        int* myf = cnt + (g * 2 + hf) * 32;
        const int* pef = cnt + (g * 2 + (hf ^ 1)) * 32;
        char* ts = smem + 32768 + wave * 512;        // per-wave [16][16] fp16
        _Float16* st = out0m + (size_t)kBH + (size_t)(b0 + rr) * kH
                       + hf * 256 + wave * 16 + cg * 4;
        // peer-staging roles (8B/thread over [16][256] peer cols)
        const size_t pg_off = (size_t)(b0 + srow) * kH + (hf ^ 1) * 256 + sunit * 4;
        const int pdoff = (srow << 10) + ((((hf ^ 1) << 9) | (sunit << 3))
                                          ^ ((srow & 7) << 4));
        // epilogue own-retain byte offsets (per j: row q*4+j, col cc)
        // prestage full h(0) into Hst[0]
        {
            u32x4 v = *(const u32x4*)(out0m + (size_t)(b0 + srow) * kH + sunit * 8);
            *(u32x4*)(smem + sdoff) = v;
        }
        __syncthreads();

        for (int t = 0; t < kT; ++t) {
            char* HR = smem + (t & 1) * 16384;
            char* HW = smem + ((t + 1) & 1) * 16384;
            float xwv[4];                            // epilogue-only, pre-gate
#pragma unroll
            for (int j = 0; j < 4; ++j)
                xwv[j] = xw[((size_t)(b0 + q * 4 + j) * kT + t) * kH + cc];
            // pre-wait: own-K MFMAs from retained own half
            floatx4 acc = {0.f, 0.f, 0.f, 0.f};
#pragma unroll
            for (int i = 0; i < 8; ++i) {
                const int ks = hf * 8 + i;
                half8 la = *(const half8*)(HR + ((rb | (ks << 6) | (q << 4)) ^ swz));
                acc = MFMA(la, wfOwn[i], acc);
            }
            // gate, then cooperative PEER-only stage (8B/thread)
            if (t > 0) {
                wait_slot(pef, t);
                u32x2 pv = *(const u32x2*)(out0m + (size_t)t * kBH + pg_off);
                *(u32x2*)(HR + pdoff) = pv;
            }
            __syncthreads();                         // S: peer staged
#pragma unroll
            for (int i = 0; i < 8; ++i) {
                const int ks = (hf ^ 1) * 8 + i;
                half8 la = *(const half8*)(HR + ((rb | (ks << 6) | (q << 4)) ^ swz));
                acc = MFMA(la, wfPeer[i], acc);
            }
            // epilogue: tanh -> ts transpose + own-retain into HW
#pragma unroll
            for (int j = 0; j < 4; ++j) {
                float v = fast_tanh(acc[j] + xwv[j]);
                const int row = q * 4 + j;
                *(_Float16*)(ts + row * 32 + r * 2) = (_Float16)v;
                *(_Float16*)(HW + (row << 10) + ((cc * 2) ^ ((row & 7) << 4))) = (_Float16)v;
            }
            asm volatile("s_waitcnt lgkmcnt(0)" ::: "memory");
            u32x2 tv = *(const u32x2*)(ts + rr * 32 + cg * 8);
            agent_store8(st, tv);                    // coalesced 8B agent store
            // publish: drain -> barrier -> one flag store (R5 recipe)
            asm volatile("" ::: "memory");
            __builtin_amdgcn_s_waitcnt(0x0F70);      // vmcnt(0)
            __syncthreads();                         // P: drained + LDS reuse fence
            if (tid == 0)
                __hip_atomic_store(myf, t + 1, __ATOMIC_RELAXED, __HIP_MEMORY_SCOPE_AGENT);
            st += kBH;
        }
    } else {
        // ===== layer 1: 4 groups x 4 quarters, 8 (hh|ih) wave pairs, full-K =====
        const int b2 = blk - 8;
        const int g = b2 >> 2, qb = b2 & 3;
        const int b0 = g * 16;
        const int ct = wave >> 1, part = wave & 1;   // pair ct, part0=hh part1=ih
        const int cc = qb * 128 + ct * 16 + r;
        half8 wfOwnQ[4], wfPeerQ[12], wfi[16];       // constant-indexed
        if (part == 0) {
#pragma unroll
            for (int i = 0; i < 4; ++i)
                wfOwnQ[i] = *(const half8*)(wh1_16 + (size_t)cc * kH
                                            + (qb * 4 + i) * 32 + q * 8);
#pragma unroll
            for (int i = 0; i < 12; ++i) {
                const int ks = i + (i >= qb * 4 ? 4 : 0);
                wfPeerQ[i] = *(const half8*)(wh1_16 + (size_t)cc * kH + ks * 32 + q * 8);
            }
        } else {
#pragma unroll
            for (int ks = 0; ks < 16; ++ks)
                wfi[ks] = *(const half8*)(wi1_16 + (size_t)cc * kH + ks * 32 + q * 8);
        }
        const float bias = (part == 0) ? (bih1[cc] + bhh1[cc]) : 0.f;
        int* myf = cnt + (8 + g * 4 + qb) * 32;
        const int* qf = cnt + (8 + g * 4) * 32;      // own-layer quarter flags
        const int* lf = cnt + (g * 2) * 32;          // layer0 half flags
        char* Ob = smem + 32768;                     // [16][1KB] out0(t+1)
        float* redp = (float*)(smem + 49152) + (ct * 256 + lane * 4);
        char* tsp = smem + 57344 + ct * 512;         // per-pair [16][16] fp16 (part0)
        _Float16* hst = h1m + (size_t)kBH + (size_t)(b0 + rr) * kH
                        + qb * 128 + ct * 16 + cg * 4;
        float* o1 = out1 + (size_t)(b0 + q * 4) * kT * kH + cc;
        // part0 peer-staging: 1536 8B-units (384 peer cols x 16 rows), 3/thread
        const int s1 = ct * 64 + lane;
        int prow3[3], pc3[3];
#pragma unroll
        for (int k3 = 0; k3 < 3; ++k3) {
            const int u = s1 + k3 * 512;
            const int row = u / 96, w = u % 96;
            prow3[k3] = row;
            pc3[k3] = w * 4 + (w * 4 >= qb * 128 ? 128 : 0);
        }
        // part1 Ob-staging roles (2 x 16B/thread) -- R13 verbatim
        const int u1 = ct * 64 + lane;
        const int osrow = u1 >> 5, osunit = u1 & 31;
        const size_t og_off = (size_t)(b0 + osrow) * kH + osunit * 16;
        char* od0 = Ob + (((osrow << 10) | (osunit << 5)) ^ ((osrow & 7) << 4));
        char* od1 = Ob + ((((osrow << 10) | (osunit << 5)) | 16) ^ ((osrow & 7) << 4));

        // prestage full h1(0) into Hst[0]
        {
            u32x4 v = *(const u32x4*)(h1m + (size_t)(b0 + srow) * kH + sunit * 8);
            *(u32x4*)(smem + sdoff) = v;
        }
        __syncthreads();

        for (int t = 0; t < kT; ++t) {
            char* HR = smem + (t & 1) * 16384;
            char* HW = smem + ((t + 1) & 1) * 16384;
            floatx4 acc = {0.f, 0.f, 0.f, 0.f};
            if (part == 0) {
                // pre-wait: own-quarter MFMAs from retained state
#pragma unroll
                for (int i = 0; i < 4; ++i) {
                    const int ks = qb * 4 + i;
                    half8 la = *(const half8*)(HR + ((rb | (ks << 6) | (q << 4)) ^ swz));
                    acc = MFMA(la, wfOwnQ[i], acc);
                }
                if (t > 0) {
                    wait_quad(qf, qb, t);
                    // stage 384 peer cols (3 x 8B/thread)
#pragma unroll
                    for (int k3 = 0; k3 < 3; ++k3) {
                        u32x2 pv = *(const u32x2*)(h1m + (size_t)t * kBH
                                     + (size_t)(b0 + prow3[k3]) * kH + pc3[k3]);
                        *(u32x2*)(HR + (prow3[k3] << 10)
                                  + ((pc3[k3] * 2) ^ ((prow3[k3] & 7) << 4))) = pv;
                    }
                }
            } else {
                wait_pair(lf, t + 1);                // layer0 slab t+1 published
                const _Float16* sl = out0m + (size_t)(t + 1) * kBH;
                half8 s0 = *(const half8*)(sl + og_off);
                half8 s1v = *(const half8*)(sl + og_off + 8);
                *(half8*)od0 = s0;
                *(half8*)od1 = s1v;
            }
            __syncthreads();                         // S: tiles staged
            if (part == 0) {
#pragma unroll
                for (int i = 0; i < 12; ++i) {
                    const int ks = i + (i >= qb * 4 ? 4 : 0);
                    half8 la = *(const half8*)(HR + ((rb | (ks << 6) | (q << 4)) ^ swz));
                    acc = MFMA(la, wfPeerQ[i], acc);
                }
            } else {
#pragma unroll
                for (int ks = 0; ks < 16; ++ks) {
                    half8 la = *(const half8*)(Ob + ((rb | (ks << 6) | (q << 4)) ^ swz));
                    acc = MFMA(la, wfi[ks], acc);
                }
                *(floatx4*)redp = acc;
            }
            __syncthreads();                         // R: partials ready
            float vj[4];
            if (part == 0) {
                floatx4 o = *(const floatx4*)redp;
#pragma unroll
                for (int j = 0; j < 4; ++j) {
                    vj[j] = fast_tanh(acc[j] + o[j] + bias);
                    const int row = q * 4 + j;
                    *(_Float16*)(tsp + row * 32 + r * 2) = (_Float16)vj[j];
                    // own-retain into next stage tile
                    *(_Float16*)(HW + (row << 10) + ((cc * 2) ^ ((row & 7) << 4)))
                        = (_Float16)vj[j];
                }
                asm volatile("s_waitcnt lgkmcnt(0)" ::: "memory");
                u32x2 tv = *(const u32x2*)(tsp + rr * 32 + cg * 8);
                agent_store8(hst, tv);               // coalesced 8B agent store
            }
            asm volatile("" ::: "memory");
            __builtin_amdgcn_s_waitcnt(0x0F70);      // vmcnt(0)
            __syncthreads();                         // P: drained + LDS reuse safe
            if (tid == 0)
                __hip_atomic_store(myf, t + 1, __ATOMIC_RELAXED, __HIP_MEMORY_SCOPE_AGENT);
            if (part == 0) {                         // out1 fp32 AFTER the flag
#pragma unroll
                for (int j = 0; j < 4; ++j)
                    o1[(size_t)j * kT * kH + (size_t)t * kH] = vj[j];
            }
            hst += kBH;
        }
    }
}

__global__ void finalize_kernel(const _Float16* __restrict__ out0m,
                                const _Float16* __restrict__ h1m,
                                float* __restrict__ out) {
    int idx = blockIdx.x * blockDim.x + threadIdx.x;  // 0 .. 65535
    float* hn = out + (size_t)kB * kT * kH;
    if (idx < kBH) hn[idx] = (float)out0m[(size_t)kT * kBH + idx];
    else hn[idx] = (float)h1m[(size_t)kT * kBH + (idx - kBH)];
}

extern "C" void kernel_launch(void* const* d_in, const int* in_sizes, int n_in,
                              void* d_out, int out_size, void* d_ws, size_t ws_size,
                              hipStream_t stream) {
    const float* x    = (const float*)d_in[0];
    const float* h0in = (const float*)d_in[1];
    const float* wih0 = (const float*)d_in[2];
    const float* whh0 = (const float*)d_in[3];
    const float* bih0 = (const float*)d_in[4];
    const float* bhh0 = (const float*)d_in[5];
    const float* wih1 = (const float*)d_in[6];
    const float* whh1 = (const float*)d_in[7];
    const float* bih1 = (const float*)d_in[8];
    const float* bhh1 = (const float*)d_in[9];
    float* out = (float*)d_out;
    char* ws = (char*)d_ws;

    _Float16* w16    = (_Float16*)(ws + W16_B);
    _Float16* wh0_16 = (_Float16*)(ws + WH0_B);
    _Float16* wi1_16 = (_Float16*)(ws + WI1_B);
    _Float16* wh1_16 = (_Float16*)(ws + WH1_B);
    _Float16* out0m  = (_Float16*)(ws + OUT0M_B);
    _Float16* h1m    = (_Float16*)(ws + H1M_B);
    int* cnt         = (int*)(ws + CNT_B);

    setup_kernel<<<2048, 256, 0, stream>>>(h0in, wih0, whh0, wih1, whh1,
                                           w16, wh0_16, wi1_16, wh1_16, out0m, h1m, cnt);
    xw_kernel<<<4096, 256, 0, stream>>>(x, w16, bih0, bhh0, out);
    scan_kernel<<<24, 1024, 0, stream>>>(out, out0m, h1m, out,
                                         wh0_16, wi1_16, wh1_16, bih1, bhh1, cnt);
    finalize_kernel<<<256, 256, 0, stream>>>(out0m, h1m, out);
}